// Round 9
// baseline (204.909 us; speedup 1.0000x reference)
//
#include <hip/hip_runtime.h>

// YOLOv1 loss: B=16384, S=7, C=30.
// R3: direct AoS loads, 75us. R5: 256-cell LDS slab, 72us. R6: 64-cell 1-wave
// blocks, 70us. All three = 193MB/70us = 2.75 TB/s read path, far under the
// 6.3 TB/s copy ceiling; VALU/LDS/HBM all idle -> bytes-in-flight bound.
// R7: persistent 1-wave blocks (10/CU), software-pipelined: regs->LDS write,
// issue next slab's loads, compute current slab while loads fly. No barriers,
// no atomics, no memset.

#define NCELLS (16384 * 49)        // 802816
#define CPS 64                     // cells per slab = lanes per wave
#define NSLABS (NCELLS / CPS)      // 12544
#define GRID 2560                  // 10 blocks/CU * 256 CU
#define SLAB_F (CPS * 30)          // 1920 floats per array slab
#define SLAB_F4 (SLAB_F / 4)       // 480 float4 per array slab
#define INV_NB (1.0f / 16384.0f)

__device__ __forceinline__ float iou_xyxy(float ax1, float ay1, float ax2, float ay2,
                                          float bx1, float by1, float bx2, float by2) {
    float ix1 = fmaxf(ax1, bx1);
    float iy1 = fmaxf(ay1, by1);
    float ix2 = fminf(ax2, bx2);
    float iy2 = fminf(ay2, by2);
    float iw = fmaxf(ix2 - ix1, 0.0f);
    float ih = fmaxf(iy2 - iy1, 0.0f);
    float inter = iw * ih;
    float a1 = (ax2 - ax1) * (ay2 - ay1);
    float a2 = (bx2 - bx1) * (by2 - by1);
    float uni = a1 + a2 - inter;
    return (inter > 0.0f) ? (inter / uni) : 0.0f;
}

__global__ __launch_bounds__(64, 3) void yolo_stage1(const float* __restrict__ pred,
                                                     const float* __restrict__ labels,
                                                     float* __restrict__ partials) {
    __shared__ float sm[2 * SLAB_F];   // 15.36 KB: [0,1920) pred, [1920,3840) labels
    const int t = threadIdx.x;

    float4 r0, r1, r2, r3, r4, r5, r6, r7, r8, r9, r10, r11, r12, r13, r14;

#define ISSUE(s)                                                                  \
    {                                                                             \
        const float4* p4 = reinterpret_cast<const float4*>(pred) + (size_t)(s)*SLAB_F4;   \
        const float4* l4 = reinterpret_cast<const float4*>(labels) + (size_t)(s)*SLAB_F4; \
        r0 = p4[0 * 64 + t];  r1 = p4[1 * 64 + t];  r2 = p4[2 * 64 + t];          \
        r3 = p4[3 * 64 + t];  r4 = p4[4 * 64 + t];  r5 = p4[5 * 64 + t];          \
        r6 = p4[6 * 64 + t];                                                      \
        r7 = (t < 32) ? p4[7 * 64 + t] : l4[7 * 64 + t - SLAB_F4];                \
        r8 = l4[8 * 64 + t - SLAB_F4];   r9 = l4[9 * 64 + t - SLAB_F4];           \
        r10 = l4[10 * 64 + t - SLAB_F4]; r11 = l4[11 * 64 + t - SLAB_F4];         \
        r12 = l4[12 * 64 + t - SLAB_F4]; r13 = l4[13 * 64 + t - SLAB_F4];         \
        r14 = l4[14 * 64 + t - SLAB_F4];                                          \
    }

    float accthr = 0.0f;
    int s = blockIdx.x;
    ISSUE(s);

    while (s < NSLABS) {
        // ---- commit slab s regs to LDS (compiler inserts vmcnt waits) ----
        float4* sm4 = reinterpret_cast<float4*>(sm);
        sm4[0 * 64 + t] = r0;   sm4[1 * 64 + t] = r1;   sm4[2 * 64 + t] = r2;
        sm4[3 * 64 + t] = r3;   sm4[4 * 64 + t] = r4;   sm4[5 * 64 + t] = r5;
        sm4[6 * 64 + t] = r6;   sm4[7 * 64 + t] = r7;   sm4[8 * 64 + t] = r8;
        sm4[9 * 64 + t] = r9;   sm4[10 * 64 + t] = r10; sm4[11 * 64 + t] = r11;
        sm4[12 * 64 + t] = r12; sm4[13 * 64 + t] = r13; sm4[14 * 64 + t] = r14;

        const int snext = s + GRID;
        if (snext < NSLABS) ISSUE(snext);   // prefetch flies during compute below

        // ---- compute cell = s*64 + t from LDS ----
        const int gcell = s * CPS + t;
        const int rem = gcell % 49;
        const float fm = (float)(rem / 7);
        const float fn = (float)(rem % 7);

        const float2* ps = reinterpret_cast<const float2*>(sm + t * 30);
        const float2* ls = reinterpret_cast<const float2*>(sm + SLAB_F + t * 30);

        float pv[30], lv[30];
#pragma unroll
        for (int k = 0; k < 15; ++k) {
            float2 a = ps[k];
            pv[2 * k] = a.x; pv[2 * k + 1] = a.y;
        }
#pragma unroll
        for (int k = 0; k < 15; ++k) {
            float2 bb = ls[k];
            lv[2 * k] = bb.x; lv[2 * k + 1] = bb.y;
        }

        // boxes (faithful to reference: /7 for x, /30 for y — the GY bug)
        float cx = (pv[0] + fm) / 7.0f;
        float cy = (pv[1] + fn) / 30.0f;
        float w = pv[2], h = pv[3];
        float p1x1 = cx - w * 0.5f, p1y1 = cy - h * 0.5f;
        float p1x2 = cx + w * 0.5f, p1y2 = cy + h * 0.5f;

        cx = (pv[5] + fm) / 7.0f;
        cy = (pv[6] + fn) / 30.0f;
        w = pv[7]; h = pv[8];
        float p2x1 = cx - w * 0.5f, p2y1 = cy - h * 0.5f;
        float p2x2 = cx + w * 0.5f, p2y2 = cy + h * 0.5f;

        cx = (lv[0] + fm) / 7.0f;
        cy = (lv[1] + fn) / 30.0f;
        w = lv[2]; h = lv[3];
        float gx1 = cx - w * 0.5f, gy1 = cy - h * 0.5f;
        float gx2 = cx + w * 0.5f, gy2 = cy + h * 0.5f;

        float iou1 = iou_xyxy(p1x1, p1y1, p1x2, p1y2, gx1, gy1, gx2, gy2);
        float iou2 = iou_xyxy(p2x1, p2y1, p2x2, p2y2, gx1, gy1, gx2, gy2);

        bool sel1 = (iou1 >= iou2);
        bool obj = (lv[4] == 1.0f);

        float dx = pv[0] - lv[0], dy = pv[1] - lv[1];
        float dw = sqrtf(pv[2]) - sqrtf(lv[2]);
        float dh = sqrtf(pv[3]) - sqrtf(lv[3]);
        float coor1 = dx * dx + dy * dy + dw * dw + dh * dh;

        dx = pv[5] - lv[5]; dy = pv[6] - lv[6];
        dw = sqrtf(pv[7]) - sqrtf(lv[7]);
        dh = sqrtf(pv[8]) - sqrtf(lv[8]);
        float coor2 = dx * dx + dy * dy + dw * dw + dh * dh;

        float coor = 5.0f * (sel1 ? coor1 : coor2);

        float d1 = pv[4] - iou1; d1 *= d1;
        float d2 = pv[9] - iou2; d2 *= d2;
        float obj_confi = sel1 ? d1 : d2;
        float noobj_at_obj = 0.5f * (sel1 ? d2 : d1);

        float cls = 0.0f;
#pragma unroll
        for (int k = 10; k < 30; ++k) {
            float d = pv[k] - lv[k];
            cls += d * d;
        }

        float noobj_at_noobj = 0.5f * (pv[4] * pv[4] + pv[9] * pv[9]);

        accthr += obj ? (coor + obj_confi + noobj_at_obj + cls) : noobj_at_noobj;

        s = snext;
    }

    // ---- one wave64 reduce at the end; one plain store per block ----
#pragma unroll
    for (int off = 32; off > 0; off >>= 1) accthr += __shfl_down(accthr, off, 64);
    if (t == 0) partials[blockIdx.x] = accthr;
#undef ISSUE
}

__global__ __launch_bounds__(256) void yolo_stage2(const float* __restrict__ partials,
                                                   float* __restrict__ out) {
    const int t = threadIdx.x;
    float acc = 0.0f;
#pragma unroll
    for (int i = 0; i < GRID / 256; ++i) {         // 10 iters, coalesced
        acc += partials[i * 256 + t];
    }
#pragma unroll
    for (int off = 32; off > 0; off >>= 1) acc += __shfl_down(acc, off, 64);

    __shared__ float sbuf[4];
    if ((t & 63) == 0) sbuf[t >> 6] = acc;
    __syncthreads();
    if (t == 0) out[0] = (sbuf[0] + sbuf[1] + sbuf[2] + sbuf[3]) * INV_NB;
}

extern "C" void kernel_launch(void* const* d_in, const int* in_sizes, int n_in,
                              void* d_out, int out_size, void* d_ws, size_t ws_size,
                              hipStream_t stream) {
    const float* pred = (const float*)d_in[0];
    const float* labels = (const float*)d_in[1];
    float* out = (float*)d_out;
    float* partials = (float*)d_ws;    // 2560 floats = 10 KB

    yolo_stage1<<<GRID, 64, 0, stream>>>(pred, labels, partials);
    yolo_stage2<<<1, 256, 0, stream>>>(partials, out);
}